// Round 20
// baseline (5725.752 us; speedup 1.0000x reference)
//
#include <hip/hip_runtime.h>

#define VV 32000
#define EE 512
#define HH 1024
#define NB 64
#define NSTEP 32

typedef __attribute__((ext_vector_type(8))) short short8;
typedef __attribute__((ext_vector_type(4))) float f32x4;
typedef unsigned long long u64;

#define MFMA16(a, b, c) __builtin_amdgcn_mfma_f32_16x16x32_bf16((a), (b), (c), 0, 0, 0)

__device__ __forceinline__ unsigned short f2bf(float f) {
  unsigned int u = __float_as_uint(f);
  u += 0x7fffu + ((u >> 16) & 1u);
  return (unsigned short)(u >> 16);
}
__device__ __forceinline__ float bf2f(unsigned short b) {
  return __uint_as_float(((unsigned int)b) << 16);
}
__device__ __forceinline__ float sigmoidf_(float x) { return 1.0f / (1.0f + expf(-x)); }
__device__ __forceinline__ unsigned int ordkey(float f) {
  unsigned int u = __float_as_uint(f);
  return u ^ ((u >> 31) ? 0xFFFFFFFFu : 0x80000000u);
}
__device__ __forceinline__ float ordkey_inv(unsigned int u) {
  return __uint_as_float((u & 0x80000000u) ? (u ^ 0x80000000u) : ~u);
}

// ---------- prep: [Wih | Whh] -> bf16 main+res fragments (vectorized) ----------
__global__ __launch_bounds__(256) void prep_wcat(const float* __restrict__ Wih,
                                                 const float* __restrict__ Whh,
                                                 unsigned short* __restrict__ wm,
                                                 unsigned short* __restrict__ wr) {
  int ub = blockIdx.x / 3, g = blockIdx.x % 3;
  for (int e = threadIdx.x; e < 48 * 64; e += 256) {
    int ks = e >> 6, lane = e & 63;
    int row = g * HH + ub * 16 + (lane & 15);
    int k0 = ks * 32 + ((lane >> 4) << 3);
    const float* srcp = (k0 < EE) ? (Wih + (size_t)row * EE + k0)
                                  : (Whh + (size_t)row * HH + (k0 - EE));
    float4 f0 = ((const float4*)srcp)[0];
    float4 f1 = ((const float4*)srcp)[1];
    float fs[8] = {f0.x, f0.y, f0.z, f0.w, f1.x, f1.y, f1.z, f1.w};
    short8 om, orr;
#pragma unroll
    for (int j = 0; j < 8; ++j) {
      unsigned short m_ = f2bf(fs[j]);
      om[j] = (short)m_;
      orr[j] = (short)f2bf(fs[j] - bf2f(m_));
    }
    size_t o8 = ((size_t)(ub * 3 + g) * 48 + ks) * 64 + lane;
    ((short8*)wm)[o8] = om;
    ((short8*)wr)[o8] = orr;
  }
}

// ---------- prep: fcW -> bf16 single fragments (vectorized) ----------
__global__ __launch_bounds__(256) void prep_wfc(const float* __restrict__ fcW,
                                                unsigned short* __restrict__ wfc) {
  int vg = blockIdx.x;
  for (int e = threadIdx.x; e < 4096; e += 256) {
    int ks = e >> 7, n = (e >> 6) & 1, lane = e & 63;
    int v = vg * 32 + n * 16 + (lane & 15);
    int k0 = ks * 32 + ((lane >> 4) << 3);
    const float4* src = (const float4*)(fcW + (size_t)v * HH + k0);
    float4 f0 = src[0];
    float4 f1 = src[1];
    float fs[8] = {f0.x, f0.y, f0.z, f0.w, f1.x, f1.y, f1.z, f1.w};
    short8 o;
#pragma unroll
    for (int j = 0; j < 8; ++j) o[j] = (short)f2bf(fs[j]);
    ((short8*)wfc)[(size_t)((vg * 32 + ks) * 2 + n) * 64 + lane] = o;
  }
}

// ---------- init: h0 (row-major + frags), x0 = emb[SOS], zero arrive[t] ----------
__global__ __launch_bounds__(256) void init_kernel(
    const float* __restrict__ enc, const float* __restrict__ emb, float* __restrict__ h4a,
    unsigned short* __restrict__ ham, unsigned short* __restrict__ har,
    unsigned short* __restrict__ xam, unsigned short* __restrict__ xar,
    int* __restrict__ arrive) {
  int i = blockIdx.x * 256 + threadIdx.x;  // 65536
  int b = i >> 10, u = i & 1023;
  float hv = enc[i];
  h4a[i] = hv;
  unsigned short m_ = f2bf(hv);
  size_t idx = (((size_t)(b >> 4) * 32 + (u >> 5)) * 64 + ((b & 15) + (((u >> 3) & 3) << 4))) * 8 + (u & 7);
  ham[idx] = m_;
  har[idx] = f2bf(hv - bf2f(m_));
  if (i < NB * EE) {
    int b2 = i >> 9, k = i & 511;
    float xv = emb[EE + k];  // token SOS=1
    unsigned short xm = f2bf(xv);
    size_t xi = (((size_t)(b2 >> 4) * 16 + (k >> 5)) * 64 + ((b2 & 15) + (((k >> 3) & 3) << 4))) * 8 + (k & 7);
    xam[xi] = xm;
    xar[xi] = f2bf(xv - bf2f(xm));
  }
  if (i < NSTEP) arrive[i] = 0;
}

// ================= GRU: 12-way K-split (768 thr), r16-identical =================
__global__ __launch_bounds__(768, 3) void gru_kernel(
    const unsigned short* __restrict__ xam, const unsigned short* __restrict__ xar,
    const unsigned short* __restrict__ him, const unsigned short* __restrict__ hir,
    const float* __restrict__ h4in, float* __restrict__ h4out,
    const unsigned short* __restrict__ wm, const unsigned short* __restrict__ wrs,
    const float* __restrict__ bih, const float* __restrict__ bhh,
    unsigned short* __restrict__ hom, unsigned short* __restrict__ hor) {
  __shared__ float red[12][16][65];  // 49,920 B
  const int tid = threadIdx.x, lane = tid & 63, w = tid >> 6;  // w 0..11
  const int ub = blockIdx.x >> 2, mg = blockIdx.x & 3;
  f32x4 aR{}, aZ{}, aNX{}, aNH{};
  const short8* XM = (const short8*)xam;
  const short8* XR = (const short8*)xar;
  const short8* HM = (const short8*)him;
  const short8* HR = (const short8*)hir;
  const short8* WM = (const short8*)wm;
  const short8* WR = (const short8*)wrs;
#pragma unroll
  for (int s = 0; s < 4; ++s) {
    int ks = w * 4 + s;
    short8 am, ar;
    if (ks < 16) {
      int o = (mg * 16 + ks) * 64 + lane;
      am = XM[o]; ar = XR[o];
    } else {
      int o = (mg * 32 + (ks - 16)) * 64 + lane;
      am = HM[o]; ar = HR[o];
    }
    {
      int o = ((ub * 3 + 0) * 48 + ks) * 64 + lane;
      short8 wmv = WM[o], wrv = WR[o];
      aR = MFMA16(am, wmv, aR); aR = MFMA16(ar, wmv, aR); aR = MFMA16(am, wrv, aR);
    }
    {
      int o = ((ub * 3 + 1) * 48 + ks) * 64 + lane;
      short8 wmv = WM[o], wrv = WR[o];
      aZ = MFMA16(am, wmv, aZ); aZ = MFMA16(ar, wmv, aZ); aZ = MFMA16(am, wrv, aZ);
    }
    {
      int o = ((ub * 3 + 2) * 48 + ks) * 64 + lane;
      short8 wmv = WM[o], wrv = WR[o];
      if (ks < 16) {
        aNX = MFMA16(am, wmv, aNX); aNX = MFMA16(ar, wmv, aNX); aNX = MFMA16(am, wrv, aNX);
      } else {
        aNH = MFMA16(am, wmv, aNH); aNH = MFMA16(ar, wmv, aNH); aNH = MFMA16(am, wrv, aNH);
      }
    }
  }
#pragma unroll
  for (int reg = 0; reg < 4; ++reg) {
    int rr = ((lane >> 4) << 2) + reg, c = lane & 15;
    red[w][rr][c] = aR[reg];
    red[w][rr][16 + c] = aZ[reg];
    red[w][rr][32 + c] = aNX[reg];
    red[w][rr][48 + c] = aNH[reg];
  }
  __syncthreads();
  if (tid < 256) {
    const int mrow = tid >> 4, uu = tid & 15;
    float R = 0.f, Z = 0.f, NX = 0.f, NH = 0.f;
#pragma unroll
    for (int q = 0; q < 12; ++q) {
      R += red[q][mrow][uu];
      Z += red[q][mrow][16 + uu];
      NX += red[q][mrow][32 + uu];
      NH += red[q][mrow][48 + uu];
    }
    const int b = mg * 16 + mrow, u = ub * 16 + uu;
    float r = sigmoidf_(R + bih[u] + bhh[u]);
    float z = sigmoidf_(Z + bih[HH + u] + bhh[HH + u]);
    float n = tanhf(NX + bih[2 * HH + u] + r * (NH + bhh[2 * HH + u]));
    float hold = h4in[b * HH + u];
    float hn = (1.0f - z) * n + z * hold;
    h4out[b * HH + u] = hn;
    unsigned short m_ = f2bf(hn);
    size_t idx = (((size_t)(b >> 4) * 32 + (u >> 5)) * 64 + ((b & 15) + (((u >> 3) & 3) << 4))) * 8 + (u & 7);
    hom[idx] = m_;
    hor[idx] = f2bf(hn - bf2f(m_));
  }
}

// ====== FC+SEL fused: wave-per-m fc (r16-identical math) + last-64-arrival handlers ===
// Protocol: stores -> threadfence (all) -> syncthreads -> tid0 atomicAdd(arrive[t]).
// Handler blocks (pos>=936, b=pos-936) spin until count==1000, acquire-fence, then run
// the complete r16 sel for their b locally (identical thr/candidates/refine/tie-break).
__global__ __launch_bounds__(256, 8) void fcsel_kernel(
    const unsigned short* __restrict__ ham,
    const unsigned short* __restrict__ wfc, const float* __restrict__ fcb,
    unsigned short* __restrict__ lgb, u64* __restrict__ blkkeys,
    int* __restrict__ arrive,
    const float* __restrict__ fcW, const float* __restrict__ emb,
    const float* __restrict__ h4,
    unsigned short* __restrict__ xam, unsigned short* __restrict__ xar, int t) {
  const int tid = threadIdx.x;
  const int lane = tid & 63, w = tid >> 6;
  const int vg = blockIdx.x;
  __shared__ u64 skey[256];
  __shared__ u64 rkey[256];
  __shared__ int scand[256];
  __shared__ int sint[3];  // [0]=pos, [1]=scnt, [2]=stok

  {  // ---- fc body (r16-identical numerics) ----
    f32x4 acc0{}, acc1{};
    const short8* HM = (const short8*)ham + (size_t)w * 2048;  // m = w
    const short8* W = (const short8*)wfc + (size_t)vg * 4096;
#pragma unroll 8
    for (int ks = 0; ks < 32; ++ks) {
      short8 am = HM[ks * 64 + lane];
      short8 w0 = W[(ks * 2 + 0) * 64 + lane];
      short8 w1 = W[(ks * 2 + 1) * 64 + lane];
      acc0 = MFMA16(am, w0, acc0);
      acc1 = MFMA16(am, w1, acc1);
    }
    const int r0 = lane >> 4, c0 = lane & 15;
    const float b0 = fcb[vg * 32 + c0];
    const float b1 = fcb[vg * 32 + 16 + c0];
    u64 kk[4];
#pragma unroll
    for (int reg = 0; reg < 4; ++reg) {
      const int b = w * 16 + r0 * 4 + reg;
      float v0 = acc0[reg] + b0;
      float v1 = acc1[reg] + b1;
      size_t ro = ((size_t)b * NSTEP + t) * VV + (size_t)vg * 32 + c0;
      lgb[ro] = f2bf(v0);
      lgb[ro + 16] = f2bf(v1);
      u64 k0 = ((u64)ordkey(v0) << 32) | (u64)(0xFFFFFFFFu - (unsigned)(vg * 32 + c0));
      u64 k1 = ((u64)ordkey(v1) << 32) | (u64)(0xFFFFFFFFu - (unsigned)(vg * 32 + 16 + c0));
      kk[reg] = k0 > k1 ? k0 : k1;
    }
#pragma unroll
    for (int d = 1; d < 16; d <<= 1)
#pragma unroll
      for (int reg = 0; reg < 4; ++reg) {
        u64 o = __shfl_xor(kk[reg], d, 64);
        if (o > kk[reg]) kk[reg] = o;
      }
    if (c0 == 0) {
#pragma unroll
      for (int reg = 0; reg < 4; ++reg)
        blkkeys[(size_t)(w * 16 + r0 * 4 + reg) * 1000 + vg] = kk[reg];
    }
  }

  // ---- release + arrival ----
  __threadfence();
  __syncthreads();
  if (tid == 0) sint[0] = atomicAdd(&arrive[t], 1);
  __syncthreads();
  const int pos = sint[0];
  if (pos < 1000 - NB) return;
  const int b = pos - (1000 - NB);

  // ---- wait for all fc blocks, acquire ----
  if (tid == 0) {
    while (atomicAdd(&arrive[t], 0) < 1000) { __builtin_amdgcn_s_sleep(8); }
  }
  __syncthreads();
  __threadfence();

  // ---- sel body for this b (r16 semantics, single block) ----
  const u64* kb = blkkeys + (size_t)b * 1000;
  u64 mk = 0;
  for (int i = tid; i < 1000; i += 256) {
    u64 k = kb[i];
    if (k > mk) mk = k;
  }
  skey[tid] = mk;
  __syncthreads();
  for (int off = 128; off > 0; off >>= 1) {
    if (tid < off && skey[tid + off] > skey[tid]) skey[tid] = skey[tid + off];
    __syncthreads();
  }
  const float Mf = ordkey_inv((unsigned)(skey[0] >> 32));
  const float thr = Mf - 0.10f;
  if (tid == 0) sint[1] = 0;
  __syncthreads();

  const short8* r8v = (const short8*)(lgb + ((size_t)b * NSTEP + t) * VV);
  for (int i = tid; i < 4000; i += 256) {
    short8 v8 = r8v[i];
#pragma unroll
    for (int e = 0; e < 8; ++e) {
      float x = bf2f((unsigned short)v8[e]);
      if (x >= thr) {
        int p = atomicAdd(&sint[1], 1);
        if (p < 256) scand[p] = i * 8 + e;
      }
    }
  }
  __syncthreads();
  int n = sint[1] < 256 ? sint[1] : 256;
  const int wv_ = tid >> 6, ln = tid & 63;
  for (int ci = wv_; ci < n; ci += 4) {
    int v = scand[ci];
    float p = 0.f;
#pragma unroll
    for (int qq = 0; qq < 16; ++qq)
      p += h4[b * HH + ln + (qq << 6)] * fcW[(size_t)v * HH + ln + (qq << 6)];
#pragma unroll
    for (int d = 1; d < 64; d <<= 1) p += __shfl_xor(p, d);
    if (ln == 0)
      rkey[ci] = ((u64)ordkey(p + fcb[v]) << 32) | (u64)(0xFFFFFFFFu - (unsigned)v);
  }
  __syncthreads();
  if (tid == 0) {
    u64 bk = 0;
    for (int ci = 0; ci < n; ++ci)
      if (rkey[ci] > bk) bk = rkey[ci];
    sint[2] = (int)(0xFFFFFFFFu - (unsigned)(bk & 0xFFFFFFFFu));
  }
  __syncthreads();

  const int tok = sint[2];
  for (int k = tid; k < EE; k += 256) {
    float xv = emb[(size_t)tok * EE + k];
    unsigned short xm = f2bf(xv);
    size_t xi = (((size_t)(b >> 4) * 16 + (k >> 5)) * 64 + ((b & 15) + (((k >> 3) & 3) << 4))) * 8 + (k & 7);
    xam[xi] = xm;
    xar[xi] = f2bf(xv - bf2f(xm));
  }
}

// ---------- final: two-pass log-softmax + hT tail (r19-identical) ----------
__global__ __launch_bounds__(256) void lsm_kernel(const unsigned short* __restrict__ lgb,
                                                  const float* __restrict__ h4,
                                                  float* __restrict__ out) {
  const int bid = blockIdx.x;
  const int tid = threadIdx.x;
  if (bid >= 2048) {  // hT tail: 256 blocks cover 65536 elements
    int i = (bid - 2048) * 256 + tid;
    out[(size_t)NB * NSTEP * VV + i] = h4[i];
    return;
  }
  const short8* r8v = (const short8*)(lgb + (size_t)bid * VV);
  float* orow = out + (size_t)bid * VV;
  __shared__ float mred[256], sred[256];

  float m = -INFINITY;
  for (int i = tid; i < VV / 8; i += 256) {
    short8 v8 = r8v[i];
    float m0 = fmaxf(bf2f((unsigned short)v8[0]), bf2f((unsigned short)v8[1]));
    float m1 = fmaxf(bf2f((unsigned short)v8[2]), bf2f((unsigned short)v8[3]));
    float m2 = fmaxf(bf2f((unsigned short)v8[4]), bf2f((unsigned short)v8[5]));
    float m3 = fmaxf(bf2f((unsigned short)v8[6]), bf2f((unsigned short)v8[7]));
    m = fmaxf(m, fmaxf(fmaxf(m0, m1), fmaxf(m2, m3)));
  }
  mred[tid] = m;
  __syncthreads();
  for (int off = 128; off > 0; off >>= 1) {
    if (tid < off) mred[tid] = fmaxf(mred[tid], mred[tid + off]);
    __syncthreads();
  }
  const float M = mred[0];

  float s0 = 0.f, s1 = 0.f, s2 = 0.f, s3 = 0.f;
  for (int i = tid; i < VV / 8; i += 256) {
    short8 v8 = r8v[i];
    s0 += __expf(bf2f((unsigned short)v8[0]) - M) + __expf(bf2f((unsigned short)v8[4]) - M);
    s1 += __expf(bf2f((unsigned short)v8[1]) - M) + __expf(bf2f((unsigned short)v8[5]) - M);
    s2 += __expf(bf2f((unsigned short)v8[2]) - M) + __expf(bf2f((unsigned short)v8[6]) - M);
    s3 += __expf(bf2f((unsigned short)v8[3]) - M) + __expf(bf2f((unsigned short)v8[7]) - M);
  }
  sred[tid] = (s0 + s1) + (s2 + s3);
  __syncthreads();
  for (int off = 128; off > 0; off >>= 1) {
    if (tid < off) sred[tid] += sred[tid + off];
    __syncthreads();
  }
  const float lse = M + logf(sred[0]);

  for (int i = tid; i < VV / 8; i += 256) {
    short8 v8 = r8v[i];
    float4 o0, o1;
    o0.x = bf2f((unsigned short)v8[0]) - lse;
    o0.y = bf2f((unsigned short)v8[1]) - lse;
    o0.z = bf2f((unsigned short)v8[2]) - lse;
    o0.w = bf2f((unsigned short)v8[3]) - lse;
    o1.x = bf2f((unsigned short)v8[4]) - lse;
    o1.y = bf2f((unsigned short)v8[5]) - lse;
    o1.z = bf2f((unsigned short)v8[6]) - lse;
    o1.w = bf2f((unsigned short)v8[7]) - lse;
    ((float4*)orow)[i * 2] = o0;
    ((float4*)orow)[i * 2 + 1] = o1;
  }
}

extern "C" void kernel_launch(void* const* d_in, const int* in_sizes, int n_in,
                              void* d_out, int out_size, void* d_ws, size_t ws_size,
                              hipStream_t stream) {
  const float* enc = (const float*)d_in[1];
  const float* emb = (const float*)d_in[2];
  const float* Wih = (const float*)d_in[3];
  const float* Whh = (const float*)d_in[4];
  const float* bih = (const float*)d_in[5];
  const float* bhh = (const float*)d_in[6];
  const float* fcW = (const float*)d_in[7];
  const float* fcb = (const float*)d_in[8];
  float* out = (float*)d_out;

  char* ws = (char*)d_ws;
  unsigned short* wfc = (unsigned short*)ws; ws += (size_t)32768000 * 2;  // 65.5 MB
  unsigned short* wcm = (unsigned short*)ws; ws += (size_t)4718592 * 2;   // 9.44 MB
  unsigned short* wcr = (unsigned short*)ws; ws += (size_t)4718592 * 2;   // 9.44 MB
  unsigned short* hAm = (unsigned short*)ws; ws += (size_t)65536 * 2;
  unsigned short* hAr = (unsigned short*)ws; ws += (size_t)65536 * 2;
  unsigned short* hBm = (unsigned short*)ws; ws += (size_t)65536 * 2;
  unsigned short* hBr = (unsigned short*)ws; ws += (size_t)65536 * 2;
  unsigned short* xam = (unsigned short*)ws; ws += (size_t)32768 * 2;
  unsigned short* xar = (unsigned short*)ws; ws += (size_t)32768 * 2;
  float* h4a = (float*)ws; ws += (size_t)NB * HH * 4;
  float* h4b = (float*)ws; ws += (size_t)NB * HH * 4;
  u64* blkkeys = (u64*)ws; ws += (size_t)NB * 1000 * 8;  // 512 KB
  int* arrive = (int*)ws; ws += (size_t)NSTEP * 4;
  unsigned short* lgb = (unsigned short*)ws; ws += (size_t)NB * NSTEP * VV * 2;  // 131 MB

  prep_wfc<<<1000, 256, 0, stream>>>(fcW, wfc);
  prep_wcat<<<192, 256, 0, stream>>>(Wih, Whh, wcm, wcr);
  init_kernel<<<256, 256, 0, stream>>>(enc, emb, h4a, hAm, hAr, xam, xar, arrive);

  for (int t = 0; t < NSTEP; ++t) {
    const float* hin = (t & 1) ? h4b : h4a;
    float* hout = (t & 1) ? h4a : h4b;
    const unsigned short* him = (t & 1) ? hBm : hAm;
    const unsigned short* hir = (t & 1) ? hBr : hAr;
    unsigned short* hom = (t & 1) ? hAm : hBm;
    unsigned short* hor = (t & 1) ? hAr : hBr;
    gru_kernel<<<256, 768, 0, stream>>>(xam, xar, him, hir, hin, hout, wcm, wcr, bih, bhh, hom, hor);
    fcsel_kernel<<<1000, 256, 0, stream>>>(hom, wfc, fcb, lgb, blkkeys, arrive,
                                           fcW, emb, hout, xam, xar, t);
  }
  lsm_kernel<<<2304, 256, 0, stream>>>(lgb, h4a, out);  // 2048 rows + 256 tail blocks
}

// Round 21
// 1647.761 us; speedup vs baseline: 3.4749x; 3.4749x over previous
//
#include <hip/hip_runtime.h>

#define VV 32000
#define EE 512
#define HH 1024
#define NB 64
#define NSTEP 32

typedef __attribute__((ext_vector_type(8))) short short8;
typedef __attribute__((ext_vector_type(4))) float f32x4;
typedef unsigned long long u64;

#define MFMA16(a, b, c) __builtin_amdgcn_mfma_f32_16x16x32_bf16((a), (b), (c), 0, 0, 0)

__device__ __forceinline__ unsigned short f2bf(float f) {
  unsigned int u = __float_as_uint(f);
  u += 0x7fffu + ((u >> 16) & 1u);
  return (unsigned short)(u >> 16);
}
__device__ __forceinline__ float bf2f(unsigned short b) {
  return __uint_as_float(((unsigned int)b) << 16);
}
__device__ __forceinline__ float sigmoidf_(float x) { return 1.0f / (1.0f + expf(-x)); }
__device__ __forceinline__ unsigned int ordkey(float f) {
  unsigned int u = __float_as_uint(f);
  return u ^ ((u >> 31) ? 0xFFFFFFFFu : 0x80000000u);
}
__device__ __forceinline__ float ordkey_inv(unsigned int u) {
  return __uint_as_float((u & 0x80000000u) ? (u ^ 0x80000000u) : ~u);
}

// ---------- prep: [Wih | Whh] -> bf16 main+res fragments (vectorized) ----------
__global__ __launch_bounds__(256) void prep_wcat(const float* __restrict__ Wih,
                                                 const float* __restrict__ Whh,
                                                 unsigned short* __restrict__ wm,
                                                 unsigned short* __restrict__ wr) {
  int ub = blockIdx.x / 3, g = blockIdx.x % 3;
  for (int e = threadIdx.x; e < 48 * 64; e += 256) {
    int ks = e >> 6, lane = e & 63;
    int row = g * HH + ub * 16 + (lane & 15);
    int k0 = ks * 32 + ((lane >> 4) << 3);
    const float* srcp = (k0 < EE) ? (Wih + (size_t)row * EE + k0)
                                  : (Whh + (size_t)row * HH + (k0 - EE));
    float4 f0 = ((const float4*)srcp)[0];
    float4 f1 = ((const float4*)srcp)[1];
    float fs[8] = {f0.x, f0.y, f0.z, f0.w, f1.x, f1.y, f1.z, f1.w};
    short8 om, orr;
#pragma unroll
    for (int j = 0; j < 8; ++j) {
      unsigned short m_ = f2bf(fs[j]);
      om[j] = (short)m_;
      orr[j] = (short)f2bf(fs[j] - bf2f(m_));
    }
    size_t o8 = ((size_t)(ub * 3 + g) * 48 + ks) * 64 + lane;
    ((short8*)wm)[o8] = om;
    ((short8*)wr)[o8] = orr;
  }
}

// ---------- prep: fcW -> bf16 single fragments (vectorized) ----------
__global__ __launch_bounds__(256) void prep_wfc(const float* __restrict__ fcW,
                                                unsigned short* __restrict__ wfc) {
  int vg = blockIdx.x;
  for (int e = threadIdx.x; e < 4096; e += 256) {
    int ks = e >> 7, n = (e >> 6) & 1, lane = e & 63;
    int v = vg * 32 + n * 16 + (lane & 15);
    int k0 = ks * 32 + ((lane >> 4) << 3);
    const float4* src = (const float4*)(fcW + (size_t)v * HH + k0);
    float4 f0 = src[0];
    float4 f1 = src[1];
    float fs[8] = {f0.x, f0.y, f0.z, f0.w, f1.x, f1.y, f1.z, f1.w};
    short8 o;
#pragma unroll
    for (int j = 0; j < 8; ++j) o[j] = (short)f2bf(fs[j]);
    ((short8*)wfc)[(size_t)((vg * 32 + ks) * 2 + n) * 64 + lane] = o;
  }
}

// ---------- init: h0 (row-major + frags), x0 = emb[SOS], zero cnt/arrive ----------
__global__ __launch_bounds__(256) void init_kernel(
    const float* __restrict__ enc, const float* __restrict__ emb, float* __restrict__ h4a,
    unsigned short* __restrict__ ham, unsigned short* __restrict__ har,
    unsigned short* __restrict__ xam, unsigned short* __restrict__ xar,
    int* __restrict__ cnt, int* __restrict__ arrive) {
  int i = blockIdx.x * 256 + threadIdx.x;  // 65536
  int b = i >> 10, u = i & 1023;
  float hv = enc[i];
  h4a[i] = hv;
  unsigned short m_ = f2bf(hv);
  size_t idx = (((size_t)(b >> 4) * 32 + (u >> 5)) * 64 + ((b & 15) + (((u >> 3) & 3) << 4))) * 8 + (u & 7);
  ham[idx] = m_;
  har[idx] = f2bf(hv - bf2f(m_));
  if (i < NB * EE) {
    int b2 = i >> 9, k = i & 511;
    float xv = emb[EE + k];  // token SOS=1
    unsigned short xm = f2bf(xv);
    size_t xi = (((size_t)(b2 >> 4) * 16 + (k >> 5)) * 64 + ((b2 & 15) + (((k >> 3) & 3) << 4))) * 8 + (k & 7);
    xam[xi] = xm;
    xar[xi] = f2bf(xv - bf2f(xm));
  }
  if (i < NB) { cnt[i] = 0; arrive[i] = 0; }
}

// ================= GRU: 12-way K-split (768 thr) for 3 waves/SIMD =================
__global__ __launch_bounds__(768, 3) void gru_kernel(
    const unsigned short* __restrict__ xam, const unsigned short* __restrict__ xar,
    const unsigned short* __restrict__ him, const unsigned short* __restrict__ hir,
    const float* __restrict__ h4in, float* __restrict__ h4out,
    const unsigned short* __restrict__ wm, const unsigned short* __restrict__ wrs,
    const float* __restrict__ bih, const float* __restrict__ bhh,
    unsigned short* __restrict__ hom, unsigned short* __restrict__ hor) {
  __shared__ float red[12][16][65];  // 49,920 B
  const int tid = threadIdx.x, lane = tid & 63, w = tid >> 6;  // w 0..11
  const int ub = blockIdx.x >> 2, mg = blockIdx.x & 3;
  f32x4 aR{}, aZ{}, aNX{}, aNH{};
  const short8* XM = (const short8*)xam;
  const short8* XR = (const short8*)xar;
  const short8* HM = (const short8*)him;
  const short8* HR = (const short8*)hir;
  const short8* WM = (const short8*)wm;
  const short8* WR = (const short8*)wrs;
#pragma unroll
  for (int s = 0; s < 4; ++s) {
    int ks = w * 4 + s;
    short8 am, ar;
    if (ks < 16) {
      int o = (mg * 16 + ks) * 64 + lane;
      am = XM[o]; ar = XR[o];
    } else {
      int o = (mg * 32 + (ks - 16)) * 64 + lane;
      am = HM[o]; ar = HR[o];
    }
    {
      int o = ((ub * 3 + 0) * 48 + ks) * 64 + lane;
      short8 wmv = WM[o], wrv = WR[o];
      aR = MFMA16(am, wmv, aR); aR = MFMA16(ar, wmv, aR); aR = MFMA16(am, wrv, aR);
    }
    {
      int o = ((ub * 3 + 1) * 48 + ks) * 64 + lane;
      short8 wmv = WM[o], wrv = WR[o];
      aZ = MFMA16(am, wmv, aZ); aZ = MFMA16(ar, wmv, aZ); aZ = MFMA16(am, wrv, aZ);
    }
    {
      int o = ((ub * 3 + 2) * 48 + ks) * 64 + lane;
      short8 wmv = WM[o], wrv = WR[o];
      if (ks < 16) {
        aNX = MFMA16(am, wmv, aNX); aNX = MFMA16(ar, wmv, aNX); aNX = MFMA16(am, wrv, aNX);
      } else {
        aNH = MFMA16(am, wmv, aNH); aNH = MFMA16(ar, wmv, aNH); aNH = MFMA16(am, wrv, aNH);
      }
    }
  }
#pragma unroll
  for (int reg = 0; reg < 4; ++reg) {
    int rr = ((lane >> 4) << 2) + reg, c = lane & 15;
    red[w][rr][c] = aR[reg];
    red[w][rr][16 + c] = aZ[reg];
    red[w][rr][32 + c] = aNX[reg];
    red[w][rr][48 + c] = aNH[reg];
  }
  __syncthreads();
  if (tid < 256) {
    const int mrow = tid >> 4, uu = tid & 15;
    float R = 0.f, Z = 0.f, NX = 0.f, NH = 0.f;
#pragma unroll
    for (int q = 0; q < 12; ++q) {
      R += red[q][mrow][uu];
      Z += red[q][mrow][16 + uu];
      NX += red[q][mrow][32 + uu];
      NH += red[q][mrow][48 + uu];
    }
    const int b = mg * 16 + mrow, u = ub * 16 + uu;
    float r = sigmoidf_(R + bih[u] + bhh[u]);
    float z = sigmoidf_(Z + bih[HH + u] + bhh[HH + u]);
    float n = tanhf(NX + bih[2 * HH + u] + r * (NH + bhh[2 * HH + u]));
    float hold = h4in[b * HH + u];
    float hn = (1.0f - z) * n + z * hold;
    h4out[b * HH + u] = hn;
    unsigned short m_ = f2bf(hn);
    size_t idx = (((size_t)(b >> 4) * 32 + (u >> 5)) * 64 + ((b & 15) + (((u >> 3) & 3) << 4))) * 8 + (u & 7);
    hom[idx] = m_;
    hor[idx] = f2bf(hn - bf2f(m_));
  }
}

// ================= FC: wave-per-m over full K, bf16 logit store ======
__global__ __launch_bounds__(256, 8) void fc_kernel(
    const unsigned short* __restrict__ ham,
    const unsigned short* __restrict__ wfc, const float* __restrict__ fcb,
    unsigned short* __restrict__ lgb, u64* __restrict__ blkkeys, int t) {
  const int tid = threadIdx.x;
  const int lane = tid & 63, w = tid >> 6;
  const int vg = blockIdx.x;
  f32x4 acc0{}, acc1{};
  const short8* HM = (const short8*)ham + (size_t)w * 2048;  // m = w
  const short8* W = (const short8*)wfc + (size_t)vg * 4096;
#pragma unroll 8
  for (int ks = 0; ks < 32; ++ks) {
    short8 am = HM[ks * 64 + lane];
    short8 w0 = W[(ks * 2 + 0) * 64 + lane];
    short8 w1 = W[(ks * 2 + 1) * 64 + lane];
    acc0 = MFMA16(am, w0, acc0);
    acc1 = MFMA16(am, w1, acc1);
  }
  const int r0 = lane >> 4, c0 = lane & 15;
  const float b0 = fcb[vg * 32 + c0];
  const float b1 = fcb[vg * 32 + 16 + c0];
  u64 kk[4];
#pragma unroll
  for (int reg = 0; reg < 4; ++reg) {
    const int b = w * 16 + r0 * 4 + reg;
    float v0 = acc0[reg] + b0;
    float v1 = acc1[reg] + b1;
    size_t ro = ((size_t)b * NSTEP + t) * VV + (size_t)vg * 32 + c0;
    lgb[ro] = f2bf(v0);
    lgb[ro + 16] = f2bf(v1);
    u64 k0 = ((u64)ordkey(v0) << 32) | (u64)(0xFFFFFFFFu - (unsigned)(vg * 32 + c0));
    u64 k1 = ((u64)ordkey(v1) << 32) | (u64)(0xFFFFFFFFu - (unsigned)(vg * 32 + 16 + c0));
    kk[reg] = k0 > k1 ? k0 : k1;
  }
#pragma unroll
  for (int d = 1; d < 16; d <<= 1)
#pragma unroll
    for (int reg = 0; reg < 4; ++reg) {
      u64 o = __shfl_xor(kk[reg], d, 64);
      if (o > kk[reg]) kk[reg] = o;
    }
  if (c0 == 0) {
#pragma unroll
    for (int reg = 0; reg < 4; ++reg)
      blkkeys[(size_t)(w * 16 + r0 * 4 + reg) * 1000 + vg] = kk[reg];
  }
}

// ================= fused SEL: 512 blocks (64 b x 8 q); last block per b refines ======
__global__ __launch_bounds__(256) void sel_kernel(
    const unsigned short* __restrict__ lgb, const u64* __restrict__ blkkeys,
    int* __restrict__ cnt, int* __restrict__ cand, int* __restrict__ arrive,
    const float* __restrict__ fcW, const float* __restrict__ fcb,
    const float* __restrict__ emb, const float* __restrict__ h4,
    unsigned short* __restrict__ xam, unsigned short* __restrict__ xar, int t) {
  const int b = blockIdx.x >> 3, q = blockIdx.x & 7;
  const int tid = threadIdx.x;
  __shared__ u64 skey[256];
  __shared__ int slast, stok;
  __shared__ u64 rkey[256];

  const u64* kb = blkkeys + (size_t)b * 1000;
  u64 mk = 0;
  for (int i = tid; i < 1000; i += 256) {
    u64 k = kb[i];
    if (k > mk) mk = k;
  }
  skey[tid] = mk;
  __syncthreads();
  for (int off = 128; off > 0; off >>= 1) {
    if (tid < off && skey[tid + off] > skey[tid]) skey[tid] = skey[tid + off];
    __syncthreads();
  }
  const float Mf = ordkey_inv((unsigned)(skey[0] >> 32));
  const float thr = Mf - 0.10f;

  const short8* r8v = (const short8*)(lgb + ((size_t)b * NSTEP + t) * VV);
  for (int i = q * 500 + tid; i < (q + 1) * 500; i += 256) {
    short8 v8 = r8v[i];
#pragma unroll
    for (int e = 0; e < 8; ++e) {
      float x = bf2f((unsigned short)v8[e]);
      if (x >= thr) {
        int p = atomicAdd(&cnt[b], 1);
        if (p < 256) atomicExch(&cand[b * 256 + p], i * 8 + e);
      }
    }
  }
  __syncthreads();
  if (tid == 0) slast = (atomicAdd(&arrive[b], 1) == 7) ? 1 : 0;
  __syncthreads();
  if (!slast) return;

  int n = atomicAdd(&cnt[b], 0);
  if (n > 256) n = 256;
  const int w = tid >> 6, ln = tid & 63;
  for (int ci = w; ci < n; ci += 4) {
    int v = atomicAdd(&cand[b * 256 + ci], 0);
    float p = 0.f;
#pragma unroll
    for (int qq = 0; qq < 16; ++qq)
      p += h4[b * HH + ln + (qq << 6)] * fcW[(size_t)v * HH + ln + (qq << 6)];
#pragma unroll
    for (int d = 1; d < 64; d <<= 1) p += __shfl_xor(p, d);
    if (ln == 0)
      rkey[ci] = ((u64)ordkey(p + fcb[v]) << 32) | (u64)(0xFFFFFFFFu - (unsigned)v);
  }
  __syncthreads();
  if (tid == 0) {
    u64 bk = 0;
    for (int ci = 0; ci < n; ++ci)
      if (rkey[ci] > bk) bk = rkey[ci];
    stok = (int)(0xFFFFFFFFu - (unsigned)(bk & 0xFFFFFFFFu));
    atomicExch(&cnt[b], 0);
    atomicExch(&arrive[b], 0);
  }
  __syncthreads();

  const int tok = stok;
  for (int k = tid; k < EE; k += 256) {
    float xv = emb[(size_t)tok * EE + k];
    unsigned short xm = f2bf(xv);
    size_t xi = (((size_t)(b >> 4) * 16 + (k >> 5)) * 64 + ((b & 15) + (((k >> 3) & 3) << 4))) * 8 + (k & 7);
    xam[xi] = xm;
    xar[xi] = f2bf(xv - bf2f(xm));
  }
}

// ---------- final pass: log-softmax from bf16 logits -> fp32 out, + hT tail ----------
__global__ __launch_bounds__(256) void lsm_kernel(const unsigned short* __restrict__ lgb,
                                                  const float* __restrict__ h4,
                                                  float* __restrict__ out) {
  const int bid = blockIdx.x;
  const int tid = threadIdx.x;
  if (bid >= 2048) {  // hT tail: 256 blocks cover 65536 elements
    int i = (bid - 2048) * 256 + tid;
    out[(size_t)NB * NSTEP * VV + i] = h4[i];
    return;
  }
  const short8* r8v = (const short8*)(lgb + (size_t)bid * VV);
  float* orow = out + (size_t)bid * VV;
  __shared__ float mred[256], sred[256];
  float m = -INFINITY, s = 0.f;
  for (int i = tid; i < VV / 8; i += 256) {
    short8 v8 = r8v[i];
#pragma unroll
    for (int c = 0; c < 8; ++c) {
      float x = bf2f((unsigned short)v8[c]);
      if (x > m) { s = s * expf(m - x) + 1.0f; m = x; }
      else s += expf(x - m);
    }
  }
  mred[tid] = m; sred[tid] = s;
  __syncthreads();
  for (int off = 128; off > 0; off >>= 1) {
    if (tid < off) {
      float m1 = mred[tid], s1 = sred[tid];
      float m2 = mred[tid + off], s2 = sred[tid + off];
      float M = fmaxf(m1, m2);
      mred[tid] = M;
      sred[tid] = s1 * expf(m1 - M) + s2 * expf(m2 - M);
    }
    __syncthreads();
  }
  const float lse = mred[0] + logf(sred[0]);
  for (int i = tid; i < VV / 8; i += 256) {
    short8 v8 = r8v[i];
    float4 o0, o1;
    o0.x = bf2f((unsigned short)v8[0]) - lse;
    o0.y = bf2f((unsigned short)v8[1]) - lse;
    o0.z = bf2f((unsigned short)v8[2]) - lse;
    o0.w = bf2f((unsigned short)v8[3]) - lse;
    o1.x = bf2f((unsigned short)v8[4]) - lse;
    o1.y = bf2f((unsigned short)v8[5]) - lse;
    o1.z = bf2f((unsigned short)v8[6]) - lse;
    o1.w = bf2f((unsigned short)v8[7]) - lse;
    ((float4*)orow)[i * 2] = o0;
    ((float4*)orow)[i * 2 + 1] = o1;
  }
}

extern "C" void kernel_launch(void* const* d_in, const int* in_sizes, int n_in,
                              void* d_out, int out_size, void* d_ws, size_t ws_size,
                              hipStream_t stream) {
  const float* enc = (const float*)d_in[1];
  const float* emb = (const float*)d_in[2];
  const float* Wih = (const float*)d_in[3];
  const float* Whh = (const float*)d_in[4];
  const float* bih = (const float*)d_in[5];
  const float* bhh = (const float*)d_in[6];
  const float* fcW = (const float*)d_in[7];
  const float* fcb = (const float*)d_in[8];
  float* out = (float*)d_out;

  char* ws = (char*)d_ws;
  unsigned short* wfc = (unsigned short*)ws; ws += (size_t)32768000 * 2;  // 65.5 MB
  unsigned short* wcm = (unsigned short*)ws; ws += (size_t)4718592 * 2;   // 9.44 MB
  unsigned short* wcr = (unsigned short*)ws; ws += (size_t)4718592 * 2;   // 9.44 MB
  unsigned short* hAm = (unsigned short*)ws; ws += (size_t)65536 * 2;
  unsigned short* hAr = (unsigned short*)ws; ws += (size_t)65536 * 2;
  unsigned short* hBm = (unsigned short*)ws; ws += (size_t)65536 * 2;
  unsigned short* hBr = (unsigned short*)ws; ws += (size_t)65536 * 2;
  unsigned short* xam = (unsigned short*)ws; ws += (size_t)32768 * 2;
  unsigned short* xar = (unsigned short*)ws; ws += (size_t)32768 * 2;
  float* h4a = (float*)ws; ws += (size_t)NB * HH * 4;
  float* h4b = (float*)ws; ws += (size_t)NB * HH * 4;
  u64* blkkeys = (u64*)ws; ws += (size_t)NB * 1000 * 8;  // 512 KB
  int* cnt = (int*)ws; ws += (size_t)NB * 4;
  int* arrive = (int*)ws; ws += (size_t)NB * 4;
  int* cand = (int*)ws; ws += (size_t)NB * 256 * 4;  // 64 KB
  unsigned short* lgb = (unsigned short*)ws; ws += (size_t)NB * NSTEP * VV * 2;  // 131 MB

  prep_wfc<<<1000, 256, 0, stream>>>(fcW, wfc);
  prep_wcat<<<192, 256, 0, stream>>>(Wih, Whh, wcm, wcr);
  init_kernel<<<256, 256, 0, stream>>>(enc, emb, h4a, hAm, hAr, xam, xar, cnt, arrive);

  for (int t = 0; t < NSTEP; ++t) {
    const float* hin = (t & 1) ? h4b : h4a;
    float* hout = (t & 1) ? h4a : h4b;
    const unsigned short* him = (t & 1) ? hBm : hAm;
    const unsigned short* hir = (t & 1) ? hBr : hAr;
    unsigned short* hom = (t & 1) ? hAm : hBm;
    unsigned short* hor = (t & 1) ? hAr : hBr;
    gru_kernel<<<256, 768, 0, stream>>>(xam, xar, him, hir, hin, hout, wcm, wcr, bih, bhh, hom, hor);
    fc_kernel<<<1000, 256, 0, stream>>>(hom, wfc, fcb, lgb, blkkeys, t);
    sel_kernel<<<512, 256, 0, stream>>>(lgb, blkkeys, cnt, cand, arrive, fcW, fcb, emb, hout, xam, xar, t);
  }
  lsm_kernel<<<2304, 256, 0, stream>>>(lgb, h4a, out);  // 2048 rows + 256 tail blocks
}